// Round 1
// baseline (447.291 us; speedup 1.0000x reference)
//
#include <hip/hip_runtime.h>
#include <math.h>

// CGBlock fused kernel for MI355X (gfx950).
//
// Shapes (from reference setup): B=16, C=256, H=W=128, G=8, Cg=32, K=4.
// out = x + rt * (top_w2 @ yt) + rs * (soft_w2 @ y)       [since rt+rs=1]
//   y[b,g,s]  = sum_c x[b,g,c,s] * softmax_c(x[b,g,:,s])[c] * soft_w1[g,c]
//   yt[b,g,s] = sum_k top4_desc(x[b,g,:,s])[k] * top_w1[g,k]
//
// Mapping: block = 512 threads = 8 waves. Wave w handles group w for the
// block's 64 consecutive spatial positions (lane = position). Each thread
// keeps its 32 group-channel values in registers (read x once), computes
// y/yt, swaps the 16 features per position through LDS, then finishes its
// own 32 output channels (write out once). All weight indices are
// wave-uniform (g via readfirstlane) -> scalar loads, so the 16-feature
// epilogue FMA uses an SGPR coefficient operand instead of LDS reads.

#define G_ 8
#define K_ 4
#define CG_ 32
#define C_ 256
#define HW_ (128 * 128)

__launch_bounds__(512)
__global__ void cgblock_kernel(const float* __restrict__ x,
                               const float* __restrict__ soft_w1,  // [G, Cg]
                               const float* __restrict__ soft_w2,  // [C, G]
                               const float* __restrict__ top_w1,   // [G, K]
                               const float* __restrict__ top_w2,   // [C, G]
                               const float* __restrict__ r,        // [2]
                               float* __restrict__ out) {
    __shared__ float Ys[G_][64];
    __shared__ float Yt[G_][64];

    const int lane = threadIdx.x & 63;
    const int g = __builtin_amdgcn_readfirstlane(threadIdx.x >> 6);  // wave id = group
    const int blk = blockIdx.x;
    const int b = blk >> 8;                  // 256 blocks per image (HW/64)
    const int s = ((blk & 255) << 6) | lane; // spatial index within image

    const int base = (b * C_ + g * CG_) * HW_ + s;
    const float* xp = x + base;

    // ---- load this group's 32 channels (coalesced: 64 lanes x 4B / instr) ----
    float v[CG_];
#pragma unroll
    for (int c = 0; c < CG_; ++c) v[c] = xp[c * HW_];

    // ---- softmax branch: y = sum_c v[c] * exp(v[c]-m)/Z * w1[g,c] ----
    float m = v[0];
#pragma unroll
    for (int c = 1; c < CG_; ++c) m = fmaxf(m, v[c]);
    float Z = 0.f, acc = 0.f;
#pragma unroll
    for (int c = 0; c < CG_; ++c) {
        float e = __expf(v[c] - m);
        Z += e;
        acc = fmaf(v[c] * e, soft_w1[g * CG_ + c], acc);  // w1 idx wave-uniform -> s_load
    }
    const float ysoft = acc / Z;

    // ---- top-k branch: branchless bubble insertion, keeps t0>=t1>=t2>=t3 ----
    float t0 = -INFINITY, t1 = -INFINITY, t2 = -INFINITY, t3 = -INFINITY;
#pragma unroll
    for (int c = 0; c < CG_; ++c) {
        const float vv = v[c];
        const float c0 = fminf(t0, vv); t0 = fmaxf(t0, vv);
        const float c1 = fminf(t1, c0); t1 = fmaxf(t1, c0);
        const float c2 = fminf(t2, c1); t2 = fmaxf(t2, c1);
        t3 = fmaxf(t3, c2);
    }
    const float ytop = t0 * top_w1[g * K_ + 0] + t1 * top_w1[g * K_ + 1] +
                       t2 * top_w1[g * K_ + 2] + t3 * top_w1[g * K_ + 3];

    // ---- exchange per-position group features through LDS ----
    Ys[g][lane] = ysoft;
    Yt[g][lane] = ytop;
    __syncthreads();

    // branch mixing weights: softmax(r) -> w[0]=rt (top), w[1]=rs (soft)
    const float e0 = __expf(r[0]);
    const float e1 = __expf(r[1]);
    const float rt = e0 / (e0 + e1);
    const float rs = e1 / (e0 + e1);

    float yf[G_], tf[G_];
#pragma unroll
    for (int gg = 0; gg < G_; ++gg) {
        yf[gg] = Ys[gg][lane] * rs;   // fold rs into soft features
        tf[gg] = Yt[gg][lane] * rt;   // fold rt into top features
    }

    // ---- epilogue: out[c] = x[c] + sum_gg (w2s[c,gg]*yf[gg] + w2t[c,gg]*tf[gg]) ----
    // All coefficient indices wave-uniform -> SGPR operand FMAs (no LDS traffic).
    float* op = out + base;
    const float* w2s = soft_w2 + g * CG_ * G_;
    const float* w2t = top_w2 + g * CG_ * G_;
#pragma unroll
    for (int c = 0; c < CG_; ++c) {
        float o = v[c];
#pragma unroll
        for (int gg = 0; gg < G_; ++gg) {
            o = fmaf(w2s[c * G_ + gg], yf[gg], o);
            o = fmaf(w2t[c * G_ + gg], tf[gg], o);
        }
        op[c * HW_] = o;  // coalesced 256B store per wave
    }
}

extern "C" void kernel_launch(void* const* d_in, const int* in_sizes, int n_in,
                              void* d_out, int out_size, void* d_ws, size_t ws_size,
                              hipStream_t stream) {
    const float* x       = (const float*)d_in[0];
    const float* soft_w1 = (const float*)d_in[1];
    const float* soft_w2 = (const float*)d_in[2];
    const float* top_w1  = (const float*)d_in[3];
    const float* top_w2  = (const float*)d_in[4];
    const float* r       = (const float*)d_in[5];
    float* out = (float*)d_out;

    // grid: B * (HW/64) = 16 * 256 = 4096 blocks; 512 threads = 8 waves (1/group)
    cgblock_kernel<<<dim3(4096), dim3(512), 0, stream>>>(
        x, soft_w1, soft_w2, top_w1, top_w2, r, out);
}

// Round 2
// 438.369 us; speedup vs baseline: 1.0204x; 1.0204x over previous
//
#include <hip/hip_runtime.h>
#include <math.h>

// CGBlock fused kernel for MI355X (gfx950) — round 2.
//
// Shapes: B=16, C=256, H=W=128, G=8, Cg=32, K=4.
// out = x + rt*(top_w2 @ yt) + rs*(soft_w2 @ y)     [rt+rs=1 folds the mix]
//
// R2 changes vs R1:
//  - float2 per thread along spatial (8 B/lane -> 512 B per wave-instr),
//    halving load/store instruction count.
//  - nontemporal loads/stores for x/out (pure streaming, no reuse).
//
// Mapping: block = 512 threads = 8 waves; wave w = group w; lane = 2
// consecutive spatial positions. Each thread keeps its 32 group-channels
// x2 positions in registers (x read once), computes softmax-dot + top-4
// dot, exchanges 16 features/position through LDS, finishes its own 32
// output channels (out written once). g is wave-uniform via readfirstlane
// so every weight index is an SGPR -> s_load + v_fmac with SGPR operand
// (no LDS/VMEM traffic in the 512-FMA epilogue).

#define G_ 8
#define K_ 4
#define CG_ 32
#define C_ 256
#define HW_ (128 * 128)

typedef __attribute__((ext_vector_type(2))) float f32x2;

__launch_bounds__(512)
__global__ void cgblock_kernel(const float* __restrict__ x,
                               const float* __restrict__ soft_w1,  // [G, Cg]
                               const float* __restrict__ soft_w2,  // [C, G]
                               const float* __restrict__ top_w1,   // [G, K]
                               const float* __restrict__ top_w2,   // [C, G]
                               const float* __restrict__ r,        // [2]
                               float* __restrict__ out) {
    __shared__ f32x2 Ys[G_][64];
    __shared__ f32x2 Yt[G_][64];

    const int lane = threadIdx.x & 63;
    const int g = __builtin_amdgcn_readfirstlane(threadIdx.x >> 6);
    const int blk = blockIdx.x;
    const int b = blk >> 7;                          // 128 blocks per image
    const int s = ((blk & 127) << 7) | (lane << 1);  // 128 positions per block

    const long base = (long)(b * C_ + g * CG_) * HW_ + s;
    const f32x2* xp = (const f32x2*)(x + base);

    // branch mixing weights: softmax(r) -> rt (top), rs (soft)
    const float e0 = __expf(r[0]);
    const float e1 = __expf(r[1]);
    const float rt = e0 / (e0 + e1);
    const float rs = e1 / (e0 + e1);

    // ---- load 32 channels x 2 positions (512 B per wave-instruction) ----
    float va[CG_], vb[CG_];
#pragma unroll
    for (int c = 0; c < CG_; ++c) {
        const f32x2 L = __builtin_nontemporal_load(xp + c * (HW_ / 2));
        va[c] = L.x;
        vb[c] = L.y;
    }

    // ---- softmax branch (both positions) ----
    float ma = va[0], mb = vb[0];
#pragma unroll
    for (int c = 1; c < CG_; ++c) {
        ma = fmaxf(ma, va[c]);
        mb = fmaxf(mb, vb[c]);
    }
    float Za = 0.f, Zb = 0.f, aa = 0.f, ab = 0.f;
#pragma unroll
    for (int c = 0; c < CG_; ++c) {
        const float w1 = soft_w1[g * CG_ + c];       // wave-uniform -> s_load
        const float ea = __expf(va[c] - ma);
        const float eb = __expf(vb[c] - mb);
        Za += ea;
        Zb += eb;
        aa = fmaf(va[c] * ea, w1, aa);
        ab = fmaf(vb[c] * eb, w1, ab);
    }
    const float ysa = aa / Za;
    const float ysb = ab / Zb;

    // ---- top-4 branch: branchless insertion network (both positions) ----
    float a0 = -INFINITY, a1 = -INFINITY, a2 = -INFINITY, a3 = -INFINITY;
    float b0 = -INFINITY, b1 = -INFINITY, b2 = -INFINITY, b3 = -INFINITY;
#pragma unroll
    for (int c = 0; c < CG_; ++c) {
        float u = va[c];
        float d0 = fminf(a0, u); a0 = fmaxf(a0, u);
        float d1 = fminf(a1, d0); a1 = fmaxf(a1, d0);
        float d2 = fminf(a2, d1); a2 = fmaxf(a2, d1);
        a3 = fmaxf(a3, d2);
        u = vb[c];
        d0 = fminf(b0, u); b0 = fmaxf(b0, u);
        d1 = fminf(b1, d0); b1 = fmaxf(b1, d0);
        d2 = fminf(b2, d1); b2 = fmaxf(b2, d1);
        b3 = fmaxf(b3, d2);
    }
    const float tw0 = top_w1[g * K_ + 0], tw1 = top_w1[g * K_ + 1];
    const float tw2 = top_w1[g * K_ + 2], tw3 = top_w1[g * K_ + 3];
    const float yta = a0 * tw0 + a1 * tw1 + a2 * tw2 + a3 * tw3;
    const float ytb = b0 * tw0 + b1 * tw1 + b2 * tw2 + b3 * tw3;

    // ---- exchange per-position group features through LDS (pre-scaled) ----
    Ys[g][lane] = f32x2{ysa * rs, ysb * rs};
    Yt[g][lane] = f32x2{yta * rt, ytb * rt};
    __syncthreads();

    f32x2 yf[G_], tf[G_];
#pragma unroll
    for (int gg = 0; gg < G_; ++gg) {
        yf[gg] = Ys[gg][lane];
        tf[gg] = Yt[gg][lane];
    }

    // ---- epilogue: out[c] = x[c] + sum_gg (w2s*yf + w2t*tf), SGPR coeffs ----
    f32x2* op = (f32x2*)(out + base);
    const float* w2s = soft_w2 + g * CG_ * G_;
    const float* w2t = top_w2 + g * CG_ * G_;
#pragma unroll
    for (int c = 0; c < CG_; ++c) {
        float oa = va[c], ob = vb[c];
#pragma unroll
        for (int gg = 0; gg < G_; ++gg) {
            const float cs = w2s[c * G_ + gg];       // wave-uniform -> s_load
            const float ct = w2t[c * G_ + gg];
            oa = fmaf(cs, yf[gg].x, oa);
            ob = fmaf(cs, yf[gg].y, ob);
            oa = fmaf(ct, tf[gg].x, oa);
            ob = fmaf(ct, tf[gg].y, ob);
        }
        __builtin_nontemporal_store(f32x2{oa, ob}, op + c * (HW_ / 2));
    }
}

extern "C" void kernel_launch(void* const* d_in, const int* in_sizes, int n_in,
                              void* d_out, int out_size, void* d_ws, size_t ws_size,
                              hipStream_t stream) {
    const float* x       = (const float*)d_in[0];
    const float* soft_w1 = (const float*)d_in[1];
    const float* soft_w2 = (const float*)d_in[2];
    const float* top_w1  = (const float*)d_in[3];
    const float* top_w2  = (const float*)d_in[4];
    const float* r       = (const float*)d_in[5];
    float* out = (float*)d_out;

    // grid: B * (HW/128) = 16 * 128 = 2048 blocks; 512 threads = 8 waves
    cgblock_kernel<<<dim3(2048), dim3(512), 0, stream>>>(
        x, soft_w1, soft_w2, top_w1, top_w2, r, out);
}